// Round 1
// baseline (331.801 us; speedup 1.0000x reference)
//
#include <hip/hip_runtime.h>
#include <hip/hip_bf16.h>

// MoE block: x[8192,1024] @ w1w3[E,1024,2816] -> swiglu -> h[8192,1408]
//            @ w2[E,1408,1024] -> out[8192,1024]. fp32 inputs (autodetected;
//            bf16 handled too). prepare converts/transposes to canonical bf16
//            [N][K] in ws (register-only transpose, no LDS), then two MFMA
//            GEMMs (m97-style, global_load_lds width-16).
// R3: gemm1 128-AGPR -> 1 wave/SIMD -> fixed R4 (tile 128x64 fused).
// R4: prepare top kernel, 2.06 TB/s; LDS transpose was scalar ds_read_u16.
// R5: register 8x4 micro-transpose.
// R6 (this round):
//   prepare: 8x8 micro-transpose (16 loads in flight, 256B read segments),
//            u16x8 stores, 3136 blocks. Theory: 26% HBM was MLP/segment-bound.
//   gemms:   T3-minimum 2-phase double buffer — prefetch tile t+1 before
//            computing tile t, ONE barrier per K-step (was 2 + immediate
//            vmcnt(0) drain of just-issued loads = m97 barrier-drain stall).

#define HIDDEN 1024
#define INTER  1408
#define NEXP   8
#define TOKENS 8192

typedef __attribute__((ext_vector_type(8))) short bf16x8;
typedef __attribute__((ext_vector_type(4))) float f32x4;
typedef __attribute__((ext_vector_type(4))) unsigned short u16x4;
typedef __attribute__((ext_vector_type(8))) unsigned short u16x8;

#define GLOAD_LDS16(g, l)                                                      \
  __builtin_amdgcn_global_load_lds(                                            \
      (const __attribute__((address_space(1))) void*)(g),                      \
      (__attribute__((address_space(3))) void*)(l), 16, 0, 0)

__device__ inline unsigned short f2bf(float f) {
  unsigned int x = __float_as_uint(f);
  x += 0x7fffu + ((x >> 16) & 1u);   // RNE
  return (unsigned short)(x >> 16);
}

// Wave-uniform fp32-vs-bf16 detection from x[0..63] viewed as fp32.
__device__ inline int detect_f32(const float* __restrict__ xf, int lane) {
  unsigned int u = __float_as_uint(xf[lane & 63]);
  int e = (u >> 23) & 0xff;
  return __popcll(__ballot(e >= 100 && e <= 140)) >= 48 ? 1 : 0;
}

// ---------- tokens_per_expert parsing (int32 / int64-lo / fallback) ----------
__device__ inline void load_tpe(const int* __restrict__ raw, int* tpe) {
  bool ok = true; int s = 0;
#pragma unroll
  for (int e = 0; e < NEXP; e++) { int v = raw[e]; tpe[e] = v; ok = ok && (v >= 0 && v <= TOKENS); s += v; }
  if (ok && s == TOKENS) return;
  ok = true; s = 0;
#pragma unroll
  for (int e = 0; e < NEXP; e++) { int v = raw[2 * e]; tpe[e] = v; ok = ok && (v >= 0 && v <= TOKENS); s += v; }
  if (ok && s == TOKENS) return;
  const int fb[NEXP] = {700, 1300, 900, 1100, 1024, 1024, 800, 1344};
#pragma unroll
  for (int e = 0; e < NEXP; e++) tpe[e] = fb[e];
}

__device__ inline bool expert_map(const int* __restrict__ tpe_raw, int rt,
                                  int& expert, int& row0, int& rows_valid) {
  int tpe[NEXP];
  load_tpe(tpe_raw, tpe);
  int acc = 0, pre = 0;
#pragma unroll
  for (int e = 0; e < NEXP; e++) {
    int nt = (tpe[e] + 127) >> 7;
    if (rt < acc + nt) {
      int ti = rt - acc;
      expert = e; row0 = pre + ti * 128; rows_valid = tpe[e] - ti * 128;
      return true;
    }
    acc += nt; pre += tpe[e];
  }
  return false;
}

// ---------- register 8x8 micro-transpose: in[R][C] -> out[C][R] bf16 ----------
// Block tile: 64 r x 256 c. Thread: mr=t&7 (8 r-rows of 8), mc=t>>3 (32 c-cols
// of 8). Reads: 16 x float4 = 16 loads in flight, 256B segments (8 lanes x 32B
// contiguous along c). Writes: 8 x ushort8 (lanes along r -> 128B segments).
// No LDS, no barrier.
__device__ inline void transpose_tile(const void* __restrict__ in,
                                      unsigned short* __restrict__ out,
                                      int R, int C, int r0, int c0,
                                      int t, int f32) {
  const int mr = t & 7, mc = t >> 3;
  const int r = r0 + mr * 8, c = c0 + mc * 8;
  u16x8 w[8];
  if (f32) {
    f32x4 f0[8], f1[8];
#pragma unroll
    for (int i = 0; i < 8; i++) {
      const float* p = (const float*)in + (size_t)(r + i) * C + c;
      f0[i] = *(const f32x4*)p;
      f1[i] = *(const f32x4*)(p + 4);
    }
#pragma unroll
    for (int j = 0; j < 4; j++)
#pragma unroll
      for (int i = 0; i < 8; i++) {
        w[j][i]     = f2bf(f0[i][j]);
        w[j + 4][i] = f2bf(f1[i][j]);
      }
  } else {
    u16x8 uv[8];
#pragma unroll
    for (int i = 0; i < 8; i++)
      uv[i] = *(const u16x8*)((const unsigned short*)in + (size_t)(r + i) * C + c);
#pragma unroll
    for (int j = 0; j < 8; j++)
#pragma unroll
      for (int i = 0; i < 8; i++) w[j][i] = uv[i][j];
  }
#pragma unroll
  for (int j = 0; j < 8; j++)
    *(u16x8*)&out[(size_t)(c + j) * R + r] = w[j];
}

// ---------- prepare: one kernel, block roles by blockIdx.x ----------
//   [0, 1024):     x -> xb bf16 elementwise (8192 elems/block, u16x8 stores)
//   [1024, 2432):  w1w3 [e][1024][2816] -> w1t [e][2816][1024]  (8 x 16 x 11)
//   [2432, 3136):  w2   [e][1408][1024] -> w2t [e][1024][1408]  (8 x 22 x 4)
__global__ __launch_bounds__(256) void prepare(
    const float* __restrict__ xf, const void* __restrict__ x,
    const void* __restrict__ w1w3, const void* __restrict__ w2,
    unsigned short* __restrict__ xb, unsigned short* __restrict__ w1t,
    unsigned short* __restrict__ w2t) {
  const int t = threadIdx.x;
  const int f32 = detect_f32(xf, t & 63);
  const int b = blockIdx.x;

  if (b < 1024) {
    const size_t base = (size_t)b * 8192;
#pragma unroll
    for (int k = 0; k < 4; k++) {
      const size_t i = base + k * 2048 + t * 8;
      u16x8 v;
      if (f32) {
        f32x4 g0 = *(const f32x4*)((const float*)x + i);
        f32x4 g1 = *(const f32x4*)((const float*)x + i + 4);
#pragma unroll
        for (int j = 0; j < 4; j++) { v[j] = f2bf(g0[j]); v[j + 4] = f2bf(g1[j]); }
      } else {
        v = *(const u16x8*)((const unsigned short*)x + i);
      }
      *(u16x8*)(xb + i) = v;
    }
    return;
  }

  if (b < 2432) {
    const int u = b - 1024;            // 8 experts x (16 ty x 11 tx) = 1408
    const int ex = u / 176, rem = u % 176;
    const int r0 = (rem / 11) * 64, c0 = (rem % 11) * 256;
    const char* in = (const char*)w1w3 +
                     (size_t)ex * 1024 * 2816 * (f32 ? 4 : 2);
    transpose_tile(in, w1t + (size_t)ex * 2816 * 1024, 1024, 2816, r0, c0, t, f32);
  } else {
    const int u = b - 2432;            // 8 experts x (22 ty x 4 tx) = 704
    const int ex = u / 88, rem = u % 88;
    const int r0 = (rem / 4) * 64, c0 = (rem % 4) * 256;
    const char* in = (const char*)w2 +
                     (size_t)ex * 1408 * 1024 * (f32 ? 4 : 2);
    transpose_tile(in, w2t + (size_t)ex * 1024 * 1408, 1408, 1024, r0, c0, t, f32);
  }
}

// ---------- GEMM1: h = silu(x@Wg) * (x@Wu), tile 128M x 64N fused ----------
// w1t: [E][2816][1024] N-major bf16. acc = 4x2 gate + 4x2 up = 64 AGPR.
// 2-phase double buffer: prefetch K-tile t+1 before computing tile t; one
// barrier per K-step (compiler's pre-barrier vmcnt(0) drain now lands AFTER
// the MFMA block -> load latency hidden under compute).
__global__ __launch_bounds__(256, 2) void moe_gemm1(
    const unsigned short* __restrict__ xb, const unsigned short* __restrict__ w1t,
    const int* __restrict__ tpe_raw, unsigned short* __restrict__ h) {
  __shared__ unsigned short As[2][128 * 32];   // 16 KB
  __shared__ unsigned short Bg[2][64 * 32];    //  8 KB
  __shared__ unsigned short Bu[2][64 * 32];    //  8 KB
  int expert, row0, rows_valid;
  if (!expert_map(tpe_raw, blockIdx.y, expert, row0, rows_valid)) return;

  const int tid = threadIdx.x;
  const int lane = tid & 63, wave = tid >> 6;
  const int wr = wave >> 1, wc = wave & 1;
  const int i0 = blockIdx.x * 64;
  const unsigned short* W = w1t + (size_t)expert * 2816 * HIDDEN;

  const int q0 = wave * 2, q1 = wave * 2 + 1;
  const int sr0 = q0 * 16 + (lane >> 2), sr1 = q1 * 16 + (lane >> 2);
  const int sb = wave * 16 + (lane >> 2);
  const int sk = (lane & 3) * 8;
  const size_t arow0 = (size_t)min(row0 + sr0, TOKENS - 1);
  const size_t arow1 = (size_t)min(row0 + sr1, TOKENS - 1);
  const unsigned short* pa0 = xb + arow0 * HIDDEN + sk;
  const unsigned short* pa1 = xb + arow1 * HIDDEN + sk;
  const unsigned short* pg = W + (size_t)(i0 + sb) * HIDDEN + sk;
  const unsigned short* pu = W + (size_t)(INTER + i0 + sb) * HIDDEN + sk;

  f32x4 accg[4][2] = {};
  f32x4 accu[4][2] = {};
  const int fr = lane & 15, fq = (lane >> 4) * 8;

  // prologue: stage K-tile 0 into buffer 0
  GLOAD_LDS16(pa0, &As[0][q0 * 512]);
  GLOAD_LDS16(pa1, &As[0][q1 * 512]);
  GLOAD_LDS16(pg, &Bg[0][wave * 512]);
  GLOAD_LDS16(pu, &Bu[0][wave * 512]);
  pa0 += 32; pa1 += 32; pg += 32; pu += 32;
  __syncthreads();   // vmcnt(0) drain: tile 0 resident

  const int NT = HIDDEN / 32;   // 32
  for (int it = 0; it < NT; ++it) {
    const int cur = it & 1, nxt = cur ^ 1;
    if (it + 1 < NT) {          // prefetch next tile (in flight during MFMA)
      GLOAD_LDS16(pa0, &As[nxt][q0 * 512]);
      GLOAD_LDS16(pa1, &As[nxt][q1 * 512]);
      GLOAD_LDS16(pg, &Bg[nxt][wave * 512]);
      GLOAD_LDS16(pu, &Bu[nxt][wave * 512]);
      pa0 += 32; pa1 += 32; pg += 32; pu += 32;
    }

    bf16x8 a[4], bg[2], bu[2];
#pragma unroll
    for (int mi = 0; mi < 4; mi++)
      a[mi] = *(const bf16x8*)&As[cur][(wr * 64 + mi * 16 + fr) * 32 + fq];
#pragma unroll
    for (int ni = 0; ni < 2; ni++) {
      bg[ni] = *(const bf16x8*)&Bg[cur][(wc * 32 + ni * 16 + fr) * 32 + fq];
      bu[ni] = *(const bf16x8*)&Bu[cur][(wc * 32 + ni * 16 + fr) * 32 + fq];
    }
#pragma unroll
    for (int mi = 0; mi < 4; mi++)
#pragma unroll
      for (int ni = 0; ni < 2; ni++) {
        accg[mi][ni] =
            __builtin_amdgcn_mfma_f32_16x16x32_bf16(a[mi], bg[ni], accg[mi][ni], 0, 0, 0);
        accu[mi][ni] =
            __builtin_amdgcn_mfma_f32_16x16x32_bf16(a[mi], bu[ni], accu[mi][ni], 0, 0, 0);
      }

    __syncthreads();  // waits prefetch landed + all reads of buf[cur] done
  }

  // C/D layout: col=lane&15, row=(lane>>4)*4+r  [measured m89/m91]
#pragma unroll
  for (int mi = 0; mi < 4; mi++)
#pragma unroll
    for (int r = 0; r < 4; r++) {
      const int row_local = wr * 64 + mi * 16 + ((lane >> 4) * 4) + r;
      if (row_local < rows_valid && row0 + row_local < TOKENS) {
        const size_t rowoff = (size_t)(row0 + row_local) * INTER;
#pragma unroll
        for (int ni = 0; ni < 2; ni++) {
          const int col = i0 + wc * 32 + ni * 16 + fr;
          const float g = accg[mi][ni][r];
          const float u = accu[mi][ni][r];
          const float sg = g / (1.0f + __expf(-g));
          h[rowoff + col] = f2bf(sg * u);
        }
      }
    }
}

// ---------- GEMM2: out = h @ w2[e], tile 128x128; out dtype inline-detected ----
__global__ __launch_bounds__(256, 2) void moe_gemm2(
    const unsigned short* __restrict__ h, const unsigned short* __restrict__ w2t,
    const int* __restrict__ tpe_raw, void* __restrict__ out,
    const float* __restrict__ xf) {
  __shared__ unsigned short As[2][128 * 32];   // 16 KB
  __shared__ unsigned short Bs[2][128 * 32];   // 16 KB
  int expert, row0, rows_valid;
  if (!expert_map(tpe_raw, blockIdx.y, expert, row0, rows_valid)) return;
  const int f32out = detect_f32(xf, threadIdx.x & 63);

  const int tid = threadIdx.x;
  const int lane = tid & 63, wave = tid >> 6;
  const int wr = wave >> 1, wc = wave & 1;
  const int n0 = blockIdx.x * 128;
  const unsigned short* W = w2t + (size_t)expert * INTER * HIDDEN;

  const int q0 = wave * 2, q1 = wave * 2 + 1;
  const int sr0 = q0 * 16 + (lane >> 2), sr1 = q1 * 16 + (lane >> 2);
  const int sk = (lane & 3) * 8;
  const size_t arow0 = (size_t)min(row0 + sr0, TOKENS - 1);
  const size_t arow1 = (size_t)min(row0 + sr1, TOKENS - 1);
  const unsigned short* pa0 = h + arow0 * INTER + sk;
  const unsigned short* pa1 = h + arow1 * INTER + sk;
  const unsigned short* pb0 = W + (size_t)(n0 + sr0) * INTER + sk;
  const unsigned short* pb1 = W + (size_t)(n0 + sr1) * INTER + sk;

  f32x4 acc[4][4] = {};
  const int fr = lane & 15, fq = (lane >> 4) * 8;

  // prologue: stage K-tile 0 into buffer 0
  GLOAD_LDS16(pa0, &As[0][q0 * 512]);
  GLOAD_LDS16(pa1, &As[0][q1 * 512]);
  GLOAD_LDS16(pb0, &Bs[0][q0 * 512]);
  GLOAD_LDS16(pb1, &Bs[0][q1 * 512]);
  pa0 += 32; pa1 += 32; pb0 += 32; pb1 += 32;
  __syncthreads();

  const int NT = INTER / 32;   // 44
  for (int it = 0; it < NT; ++it) {
    const int cur = it & 1, nxt = cur ^ 1;
    if (it + 1 < NT) {
      GLOAD_LDS16(pa0, &As[nxt][q0 * 512]);
      GLOAD_LDS16(pa1, &As[nxt][q1 * 512]);
      GLOAD_LDS16(pb0, &Bs[nxt][q0 * 512]);
      GLOAD_LDS16(pb1, &Bs[nxt][q1 * 512]);
      pa0 += 32; pa1 += 32; pb0 += 32; pb1 += 32;
    }

    bf16x8 a[4], bb[4];
#pragma unroll
    for (int mi = 0; mi < 4; mi++)
      a[mi] = *(const bf16x8*)&As[cur][(wr * 64 + mi * 16 + fr) * 32 + fq];
#pragma unroll
    for (int ni = 0; ni < 4; ni++)
      bb[ni] = *(const bf16x8*)&Bs[cur][(wc * 64 + ni * 16 + fr) * 32 + fq];
#pragma unroll
    for (int mi = 0; mi < 4; mi++)
#pragma unroll
      for (int ni = 0; ni < 4; ni++)
        acc[mi][ni] =
            __builtin_amdgcn_mfma_f32_16x16x32_bf16(a[mi], bb[ni], acc[mi][ni], 0, 0, 0);

    __syncthreads();
  }

#pragma unroll
  for (int mi = 0; mi < 4; mi++)
#pragma unroll
    for (int r = 0; r < 4; r++) {
      const int row_local = wr * 64 + mi * 16 + ((lane >> 4) * 4) + r;
      if (row_local < rows_valid && row0 + row_local < TOKENS) {
        const size_t rowoff = (size_t)(row0 + row_local) * HIDDEN;
#pragma unroll
        for (int ni = 0; ni < 4; ni++) {
          const int col = n0 + wc * 64 + ni * 16 + fr;
          if (f32out)
            ((float*)out)[rowoff + col] = acc[mi][ni][r];
          else
            ((unsigned short*)out)[rowoff + col] = f2bf(acc[mi][ni][r]);
        }
      }
    }
}

extern "C" void kernel_launch(void* const* d_in, const int* in_sizes, int n_in,
                              void* d_out, int out_size, void* d_ws, size_t ws_size,
                              hipStream_t stream) {
  const void* x = d_in[0];
  const void* w1w3 = d_in[1];
  const void* w2 = d_in[2];
  const int* tpe = (const int*)d_in[3];
  const float* xf = (const float*)d_in[0];

  // ws: xb[8192][1024] | w1t[8][2816][1024] | w2t[8][1024][1408] | h[8192][1408]
  const size_t XB_BYTES = (size_t)TOKENS * HIDDEN * 2;         // 16,777,216
  const size_t W1T_BYTES = (size_t)NEXP * 2816 * HIDDEN * 2;   // 46,137,344
  const size_t W2T_BYTES = (size_t)NEXP * INTER * HIDDEN * 2;  // 23,068,672
  char* ws = (char*)d_ws;
  unsigned short* xb = (unsigned short*)ws;
  unsigned short* w1t = (unsigned short*)(ws + XB_BYTES);
  unsigned short* w2t = (unsigned short*)(ws + XB_BYTES + W1T_BYTES);
  unsigned short* h = (unsigned short*)(ws + XB_BYTES + W1T_BYTES + W2T_BYTES);

  prepare<<<3136, 256, 0, stream>>>(xf, x, w1w3, w2, xb, w1t, w2t);
  moe_gemm1<<<dim3(INTER / 64, 72), 256, 0, stream>>>(xb, w1t, tpe, h);
  moe_gemm2<<<dim3(HIDDEN / 128, 72), 256, 0, stream>>>(h, w2t, tpe, d_out, xf);
}